// Round 4
// baseline (144.567 us; speedup 1.0000x reference)
//
#include <hip/hip_runtime.h>
#include <hip/hip_bf16.h>

#define D 512
#define NWAY 64
#define KSHOT 16
#define NQ 8192
#define LSA 520   // LDS A stride (bf16 elems): 1040 B -> uniform banks for b128

typedef __bf16 bf16_t;
typedef __bf16 bf16x4_t __attribute__((ext_vector_type(4)));
typedef __bf16 bf16x8_t __attribute__((ext_vector_type(8)));
typedef float  f32x4    __attribute__((ext_vector_type(4)));

// ---------------------------------------------------------------- KP1
// blocks 0..63: class means cm[64][512]; blocks 64..319: W -> bf16 (Wb rows 0..511)
__global__ void k_prep1(const float* __restrict__ sup, const float* __restrict__ W,
                        float* __restrict__ cm, bf16_t* __restrict__ Wb)
{
    const int b = blockIdx.x, t = threadIdx.x;
    if (b < NWAY) {
        const float2* base = (const float2*)(sup + (size_t)b * KSHOT * D) + t;
        float sx = 0.f, sy = 0.f;
#pragma unroll
        for (int j = 0; j < KSHOT; ++j) { float2 v = base[j * (D / 2)]; sx += v.x; sy += v.y; }
        float2 r; r.x = sx * (1.0f / KSHOT); r.y = sy * (1.0f / KSHOT);
        ((float2*)(cm + (size_t)b * D))[t] = r;
    } else {
        const int idx = (b - NWAY) * 1024 + t * 4;   // 256 blocks x 1024 = 262144 = D*D
        float4 v = *(const float4*)(W + idx);
        bf16x4_t h = { (bf16_t)v.x, (bf16_t)v.y, (bf16_t)v.z, (bf16_t)v.w };
        *(bf16x4_t*)(Wb + idx) = h;
    }
}

// ---------------------------------------------------------------- KP2
// P[c][j] = cm_c . W_row_j + b_j   (fp32, exact-ish). grid 64x8, 256 thr.
__global__ void k_prep2(const float* __restrict__ cm, const float* __restrict__ W,
                        const float* __restrict__ bias, float* __restrict__ P)
{
    const int c = blockIdx.x >> 3, jc = blockIdx.x & 7;
    const int t = threadIdx.x;
    const int jl = t >> 2, q = t & 3;          // 64 j per block, K split x4
    const int j = jc * 64 + jl;
    const f32x4* wr = (const f32x4*)(W + (size_t)j * D + q * 128);
    const f32x4* cr = (const f32x4*)(cm + (size_t)c * D + q * 128);
    float s = 0.f;
#pragma unroll
    for (int i = 0; i < 32; ++i) {
        f32x4 a = cr[i], w = wr[i];
        s += a[0]*w[0] + a[1]*w[1] + a[2]*w[2] + a[3]*w[3];
    }
    s += __shfl_xor(s, 1); s += __shfl_xor(s, 2);
    if (q == 0) P[(size_t)c * D + j] = s + bias[j];
}

// ---------------------------------------------------------------- KP3
// G[c][k] = sum_j P[c][j] W[j][k] -> Wb rows 512..575 (bf16);
// ph[c] = ||p_c||^2 - 2 b.p_c (computed by kc==0 blocks). grid 64x8, 256 thr.
__global__ void k_prep3(const float* __restrict__ P, const float* __restrict__ W,
                        const float* __restrict__ bias, bf16_t* __restrict__ Wb,
                        float* __restrict__ ph)
{
    __shared__ float sG[4][64];
    __shared__ float sph[4];
    const int c = blockIdx.x >> 3, kc = blockIdx.x & 7;
    const int t = threadIdx.x;
    const int kl = t & 63, s4 = t >> 6;        // 64 k-cols, j split x4
    const float* Pc = P + (size_t)c * D;
    float g = 0.f;
    for (int j = s4 * 128; j < s4 * 128 + 128; ++j)
        g += Pc[j] * W[(size_t)j * D + kc * 64 + kl];
    sG[s4][kl] = g;
    if (kc == 0) {
        float v1 = Pc[2 * t], v2 = Pc[2 * t + 1];
        float psum = v1 * v1 + v2 * v2 - 2.0f * (bias[2 * t] * v1 + bias[2 * t + 1] * v2);
#pragma unroll
        for (int off = 32; off; off >>= 1) psum += __shfl_xor(psum, off);
        if ((t & 63) == 0) sph[t >> 6] = psum;
    }
    __syncthreads();
    if (t < 64)
        Wb[(size_t)(D + c) * D + kc * 64 + t] = (bf16_t)(sG[0][t] + sG[1][t] + sG[2][t] + sG[3][t]);
    if (kc == 0 && t == 0) ph[c] = sph[0] + sph[1] + sph[2] + sph[3];
}

// ---------------------------------------------------------------- KM
// dists[8192][64] in one pass: A-panel (32 query rows, bf16) LDS-resident,
// barrier-free 144-step MFMA loop vs Bcat=[W;G] (L2-hot), qn in registers.
// grid 256 (1 block/CU), 512 thr = 8 waves (2 m-frags x 4 n-splits of 144).
__global__ __launch_bounds__(512, 2) void k_main(
    const float* __restrict__ query, const bf16_t* __restrict__ Wb,
    const float* __restrict__ bias,  const float* __restrict__ ph,
    float* __restrict__ out)
{
    __shared__ bf16_t As[32 * LSA];   // 33,280 B
    __shared__ float qln[4][32];
    __shared__ float phs[NWAY];

    const int tid = threadIdx.x;
    const int m0 = blockIdx.x * 32;

    if (tid < NWAY) phs[tid] = ph[tid];

    // ---- stage A once: 32 rows x 512 K fp32 -> bf16 LDS (coalesced 2KB/wave) ----
#pragma unroll
    for (int p = 0; p < 4; ++p) {
        const int row = p * 8 + (tid >> 6);
        const int col = (tid & 63) * 8;
        const float* src = query + (size_t)(m0 + row) * D + col;
        f32x4 v0 = *(const f32x4*)(src);
        f32x4 v1 = *(const f32x4*)(src + 4);
        bf16x8_t h = { (bf16_t)v0[0], (bf16_t)v0[1], (bf16_t)v0[2], (bf16_t)v0[3],
                       (bf16_t)v1[0], (bf16_t)v1[1], (bf16_t)v1[2], (bf16_t)v1[3] };
        *(bf16x8_t*)(As + row * LSA + col) = h;
    }
    __syncthreads();

    const int l = tid & 63;
    const int w = tid >> 6, wm = w & 1, wn = w >> 1;
    const int r15 = l & 15, quad = l >> 4;

    const bf16_t* Ab = As + (wm * 16 + r15) * LSA + quad * 8;
    const bf16_t* Bb[9];
#pragma unroll
    for (int t = 0; t < 9; ++t)
        Bb[t] = Wb + (size_t)((wn * 9 + t) * 16 + r15) * D + quad * 8;

    f32x4 acc[9];
#pragma unroll
    for (int t = 0; t < 9; ++t) acc[t] = (f32x4){0.f, 0.f, 0.f, 0.f};

    // ---- barrier-free inner loop: 16 k-tiles x 9 col-tiles ----
#pragma unroll
    for (int k = 0; k < 16; ++k) {
        bf16x8_t a = *(const bf16x8_t*)(Ab + k * 32);
#pragma unroll
        for (int t = 0; t < 9; ++t) {
            bf16x8_t b = *(const bf16x8_t*)(Bb[t] + k * 32);
            acc[t] = __builtin_amdgcn_mfma_f32_16x16x32_bf16(a, b, acc[t], 0, 0, 0);
        }
    }

    // ---- qn partials: sum (e+bias)^2 over this wave's W-cols ----
    const int nW = (wn == 3) ? 5 : 9;          // wn==3 owns tiles 27..31(W) + 32..35(G)
    float qp[4] = {0.f, 0.f, 0.f, 0.f};
    for (int t = 0; t < nW; ++t) {
        float bv = bias[wn * 144 + t * 16 + r15];
#pragma unroll
        for (int reg = 0; reg < 4; ++reg) {
            float v = acc[t][reg] + bv;
            qp[reg] += v * v;
        }
    }
#pragma unroll
    for (int reg = 0; reg < 4; ++reg) {
        float s = qp[reg];
        s += __shfl_xor(s, 1); s += __shfl_xor(s, 2);
        s += __shfl_xor(s, 4); s += __shfl_xor(s, 8);
        if (r15 == 0) qln[wn][wm * 16 + quad * 4 + reg] = s;
    }
    __syncthreads();

    // ---- wn==3 waves: combine qn, add ph, write dists ----
    if (wn == 3) {
#pragma unroll
        for (int reg = 0; reg < 4; ++reg) {
            const int row = wm * 16 + quad * 4 + reg;
            float qt = qln[0][row] + qln[1][row] + qln[2][row] + qln[3][row];
#pragma unroll
            for (int tg = 0; tg < 4; ++tg) {
                int c = tg * 16 + r15;
                out[(size_t)(m0 + row) * NWAY + c] = qt + phs[c] - 2.0f * acc[5 + tg][reg];
            }
        }
    }
}

// ---------------------------------------------------------------- launch
extern "C" void kernel_launch(void* const* d_in, const int* in_sizes, int n_in,
                              void* d_out, int out_size, void* d_ws, size_t ws_size,
                              hipStream_t stream)
{
    const float* support = (const float*)d_in[0];
    const float* query   = (const float*)d_in[1];
    const float* W       = (const float*)d_in[2];
    const float* bias    = (const float*)d_in[3];
    float* out = (float*)d_out;

    char* ws = (char*)d_ws;
    float*  cm = (float*)ws;                       // 131,072 B
    float*  P  = (float*)(ws + 131072);            // 131,072 B
    bf16_t* Wb = (bf16_t*)(ws + 262144);           // 576*512*2 = 589,824 B
    float*  ph = (float*)(ws + 262144 + 589824);   // 256 B

    k_prep1<<<NWAY + 256, 256, 0, stream>>>(support, W, cm, Wb);
    k_prep2<<<NWAY * 8, 256, 0, stream>>>(cm, W, bias, P);
    k_prep3<<<NWAY * 8, 256, 0, stream>>>(P, W, bias, Wb, ph);
    k_main<<<NQ / 32, 512, 0, stream>>>(query, Wb, bias, ph, out);
}